// Round 5
// baseline (310.523 us; speedup 1.0000x reference)
//
#include <hip/hip_runtime.h>
#include <hip/hip_bf16.h>

#define N 8192
#define D 1024

static constexpr float TEMP = 0.1f;
static constexpr float KEEP = 0.9f;
static constexpr float EPSN = 1e-8f;

typedef __attribute__((ext_vector_type(8))) short bf16x8;
typedef __attribute__((ext_vector_type(4))) float f32x4;

__device__ __forceinline__ void gload_lds16(const void* gsrc, void* ldst) {
  __builtin_amdgcn_global_load_lds(
      (const __attribute__((address_space(1))) void*)gsrc,
      (__attribute__((address_space(3))) void*)ldst, 16, 0, 0);
}

// ---------------- Kernel A: norms + diag + bf16 convert (scales folded) ----
struct bf4pack { __hip_bfloat16 v[4]; };

__global__ __launch_bounds__(256) void UCR_prep(
    const float* __restrict__ inputs, const float* __restrict__ noise,
    __hip_bfloat16* __restrict__ aB, __hip_bfloat16* __restrict__ bB,
    float* __restrict__ diag, float* __restrict__ S)
{
  const int row = blockIdx.x;
  const int t = threadIdx.x;
  const float4 x = ((const float4*)(inputs + (size_t)row * D))[t];
  const float4 u = ((const float4*)(noise  + (size_t)row * D))[t];
  const float inv_keep = 1.0f / KEEP;
  float4 e;
  e.x = (u.x < KEEP) ? x.x * inv_keep : 0.0f;
  e.y = (u.y < KEEP) ? x.y * inv_keep : 0.0f;
  e.z = (u.z < KEEP) ? x.z * inv_keep : 0.0f;
  e.w = (u.w < KEEP) ? x.w * inv_keep : 0.0f;

  float sx  = x.x*x.x + x.y*x.y + x.z*x.z + x.w*x.w;
  float se  = e.x*e.x + e.y*e.y + e.z*e.z + e.w*e.w;
  float sxe = x.x*e.x + x.y*e.y + x.z*e.z + x.w*e.w;

  #pragma unroll
  for (int off = 1; off < 64; off <<= 1) {
    sx  += __shfl_xor(sx, off);
    se  += __shfl_xor(se, off);
    sxe += __shfl_xor(sxe, off);
  }
  __shared__ float red[3][4];
  const int wid = t >> 6, lane = t & 63;
  if (lane == 0) { red[0][wid] = sx; red[1][wid] = se; red[2][wid] = sxe; }
  __syncthreads();
  sx  = red[0][0] + red[0][1] + red[0][2] + red[0][3];
  se  = red[1][0] + red[1][1] + red[1][2] + red[1][3];
  sxe = red[2][0] + red[2][1] + red[2][2] + red[2][3];

  const float na = fmaxf(sqrtf(sx), EPSN);
  const float nb = fmaxf(sqrtf(se), EPSN);
  const float sa = 1.0f / (na * TEMP);
  const float sb = 1.0f / nb;
  if (t == 0) { diag[row] = sxe / (na * nb * TEMP); S[row] = 0.0f; }

  bf4pack pa, pb;
  pa.v[0] = __float2bfloat16(x.x * sa); pa.v[1] = __float2bfloat16(x.y * sa);
  pa.v[2] = __float2bfloat16(x.z * sa); pa.v[3] = __float2bfloat16(x.w * sa);
  pb.v[0] = __float2bfloat16(e.x * sb); pb.v[1] = __float2bfloat16(e.y * sb);
  pb.v[2] = __float2bfloat16(e.z * sb); pb.v[3] = __float2bfloat16(e.w * sb);
  ((bf4pack*)(aB + (size_t)row * D))[t] = pa;
  ((bf4pack*)(bB + (size_t)row * D))[t] = pb;
}

// ---------------- Kernel B: 256x256, BK=64, 8-phase, 2-tile-deep prefetch --
// Per tile kt (buffer kt&1): P1 reads aLo+bLo, P2 aHi, P3 bHi; MFMA quadrant
// per phase. Stage tile kt+2 (SAME-parity buffer) during kt: A-halves at P3
// (A-region dead: all waves' A ds_reads drained at P2 lgkm0, enforced by
// P2-close barrier), B-halves at P4 (B dead after P3-close). vmcnt(8) at P4
// retires tile kt+1's loads, issued 5-6 phases earlier -> HBM latency hidden,
// 8 loads always in flight. Swizzle: 128 B rows, byte ^= (row&7)<<4,
// both-sides involution (linear gload dest + inverse-swizzled global src).
__global__ __launch_bounds__(512, 2) void UCR_gemm(
    const __hip_bfloat16* __restrict__ Aw, const __hip_bfloat16* __restrict__ Bw,
    float* __restrict__ S)
{
  __shared__ char lds[131072];

  const int t = threadIdx.x;
  const int lane = t & 63;
  const int wid = t >> 6;      // 0..7
  const int wm = wid >> 2;     // 0..1  row half (128 rows)
  const int wn = wid & 3;      // 0..3  col quarter (64 cols)

  // XCD-aware swizzle: 1024 blocks, 1024 % 8 == 0 -> bijective
  const int bid = blockIdx.x;
  const int sw = (bid & 7) * 128 + (bid >> 3);
  const int tm = sw >> 5;
  const int tn = sw & 31;

  const char* Ag = (const char*)(Aw + (size_t)tm * 256 * D);
  const char* Bg = (const char*)(Bw + (size_t)tn * 256 * D);

  // staging map: linear LDS dest x -> inverse-swizzled global src (rule 21)
  const unsigned x0 = (unsigned)t * 16u, x1 = (unsigned)(t + 512) * 16u;
  const unsigned l0 = x0 ^ (((x0 >> 7) & 7u) << 4);
  const unsigned l1 = x1 ^ (((x1 >> 7) & 7u) << 4);
  const unsigned off0 = (l0 >> 7) * 2048u + (l0 & 127u);
  const unsigned off1 = (l1 >> 7) * 2048u + (l1 & 127u);

  // T: K-tile index; op: 0=A 1=B; h: 128-row half
#define STAGE(T, op, h) do {                                                 \
    const char* _g = (op) ? Bg : Ag;                                         \
    char* _L = lds + (((T) & 1) << 16) + ((op) << 15) + ((h) << 14);         \
    const size_t _go = (size_t)((h) * 128) * 2048 + (size_t)(T) * 128;       \
    gload_lds16(_g + _go + off0, _L + x0);                                   \
    gload_lds16(_g + _go + off1, _L + x1);                                   \
  } while (0)

  const int ln = lane & 15;
  const int cq = lane >> 4;
  const int swb = (ln & 7) << 4;
  const int colk0 = (cq * 16) ^ swb;
  const int colk1 = (64 + cq * 16) ^ swb;

  bf16x8 aLo[4][2], aHi[4][2], bLo[2][2], bHi[2][2];
  f32x4 acc[8][4] = {};

  // prologue: tiles 0 and 1 fully staged (16 loads in flight)
  STAGE(0, 0, 0); STAGE(0, 0, 1); STAGE(0, 1, 0); STAGE(0, 1, 1);
  STAGE(1, 0, 0); STAGE(1, 0, 1); STAGE(1, 1, 0); STAGE(1, 1, 1);
  asm volatile("s_waitcnt vmcnt(8)" ::: "memory");
  __builtin_amdgcn_s_barrier();

  for (int kt = 0; kt < 16; ++kt) {
    const char* LA = lds + ((kt & 1) << 16);
    const char* LB = LA + 32768;
    const int rA = wm * 128 + ln;
    const int rB = wn * 64 + ln;

    // ---- P1: read aLo(8) + bLo(4); MFMA Q0 (m0-3, n0-1)
    #pragma unroll
    for (int m = 0; m < 4; ++m) {
      const int rb = (rA + m * 16) << 7;
      aLo[m][0] = *(const bf16x8*)(LA + rb + colk0);
      aLo[m][1] = *(const bf16x8*)(LA + rb + colk1);
    }
    #pragma unroll
    for (int n = 0; n < 2; ++n) {
      const int rb = (rB + n * 16) << 7;
      bLo[n][0] = *(const bf16x8*)(LB + rb + colk0);
      bLo[n][1] = *(const bf16x8*)(LB + rb + colk1);
    }
    asm volatile("s_waitcnt lgkmcnt(8)" ::: "memory");
    __builtin_amdgcn_s_barrier();
    asm volatile("s_waitcnt lgkmcnt(0)" ::: "memory");
    __builtin_amdgcn_sched_barrier(0);
    __builtin_amdgcn_s_setprio(1);
    #pragma unroll
    for (int ks = 0; ks < 2; ++ks)
      #pragma unroll
      for (int m = 0; m < 4; ++m)
        #pragma unroll
        for (int n = 0; n < 2; ++n)
          acc[m][n] = __builtin_amdgcn_mfma_f32_16x16x32_bf16(
              aLo[m][ks], bLo[n][ks], acc[m][n], 0, 0, 0);
    __builtin_amdgcn_s_setprio(0);
    __builtin_amdgcn_s_barrier();

    // ---- P2: read aHi(8); MFMA Q1 (m4-7, n0-1)
    #pragma unroll
    for (int m = 0; m < 4; ++m) {
      const int rb = (rA + 64 + m * 16) << 7;
      aHi[m][0] = *(const bf16x8*)(LA + rb + colk0);
      aHi[m][1] = *(const bf16x8*)(LA + rb + colk1);
    }
    __builtin_amdgcn_s_barrier();
    asm volatile("s_waitcnt lgkmcnt(0)" ::: "memory");
    __builtin_amdgcn_sched_barrier(0);
    __builtin_amdgcn_s_setprio(1);
    #pragma unroll
    for (int ks = 0; ks < 2; ++ks)
      #pragma unroll
      for (int m = 0; m < 4; ++m)
        #pragma unroll
        for (int n = 0; n < 2; ++n)
          acc[4 + m][n] = __builtin_amdgcn_mfma_f32_16x16x32_bf16(
              aHi[m][ks], bLo[n][ks], acc[4 + m][n], 0, 0, 0);
    __builtin_amdgcn_s_setprio(0);
    __builtin_amdgcn_s_barrier();   // closes P2: A-region of this buffer dead

    // ---- P3: read bHi(4); stage (kt+2) A h0+h1 into dead A-region; MFMA Q2
    #pragma unroll
    for (int n = 0; n < 2; ++n) {
      const int rb = (rB + 32 + n * 16) << 7;
      bHi[n][0] = *(const bf16x8*)(LB + rb + colk0);
      bHi[n][1] = *(const bf16x8*)(LB + rb + colk1);
    }
    if (kt < 14) { STAGE(kt + 2, 0, 0); STAGE(kt + 2, 0, 1); }
    __builtin_amdgcn_s_barrier();
    asm volatile("s_waitcnt lgkmcnt(0)" ::: "memory");
    __builtin_amdgcn_sched_barrier(0);
    __builtin_amdgcn_s_setprio(1);
    #pragma unroll
    for (int ks = 0; ks < 2; ++ks)
      #pragma unroll
      for (int m = 0; m < 4; ++m)
        #pragma unroll
        for (int n = 0; n < 2; ++n)
          acc[m][2 + n] = __builtin_amdgcn_mfma_f32_16x16x32_bf16(
              aLo[m][ks], bHi[n][ks], acc[m][2 + n], 0, 0, 0);
    __builtin_amdgcn_s_setprio(0);
    __builtin_amdgcn_s_barrier();   // closes P3: B-region of this buffer dead

    // ---- P4: stage (kt+2) B h0+h1; MFMA Q3; vmcnt retires tile kt+1's loads
    if (kt < 14) { STAGE(kt + 2, 1, 0); STAGE(kt + 2, 1, 1); }
    __builtin_amdgcn_s_setprio(1);
    #pragma unroll
    for (int ks = 0; ks < 2; ++ks)
      #pragma unroll
      for (int m = 0; m < 4; ++m)
        #pragma unroll
        for (int n = 0; n < 2; ++n)
          acc[4 + m][2 + n] = __builtin_amdgcn_mfma_f32_16x16x32_bf16(
              aHi[m][ks], bHi[n][ks], acc[4 + m][2 + n], 0, 0, 0);
    __builtin_amdgcn_s_setprio(0);
    if (kt < 14)       asm volatile("s_waitcnt vmcnt(8)" ::: "memory");
    else if (kt == 14) asm volatile("s_waitcnt vmcnt(0)" ::: "memory");
    if (kt < 15) __builtin_amdgcn_s_barrier();
  }
#undef STAGE

  // epilogue: C/D frag layout col=lane&15, row=(lane>>4)*4+i
  const int g = lane >> 4;
  const int c = lane & 15;
  const int rowbase = tm * 256 + wm * 128;
  #pragma unroll
  for (int m = 0; m < 8; ++m) {
    #pragma unroll
    for (int i = 0; i < 4; ++i) {
      float s = 0.0f;
      #pragma unroll
      for (int n = 0; n < 4; ++n) s += __expf(acc[m][n][i]);
      #pragma unroll
      for (int off = 1; off < 16; off <<= 1) s += __shfl_xor(s, off);
      if (c == 0) atomicAdd(&S[rowbase + m * 16 + g * 4 + i], s);
    }
  }
}

// ---------------- Kernel C: loss = mean(log(S) - diag), single block -------
__global__ __launch_bounds__(256) void UCR_loss(
    const float* __restrict__ S, const float* __restrict__ diag,
    float* __restrict__ out)
{
  float acc = 0.0f;
  for (int i = threadIdx.x; i < N; i += 256)
    acc += logf(S[i]) - diag[i];
  #pragma unroll
  for (int off = 1; off < 64; off <<= 1) acc += __shfl_xor(acc, off);
  __shared__ float r[4];
  if ((threadIdx.x & 63) == 0) r[threadIdx.x >> 6] = acc;
  __syncthreads();
  if (threadIdx.x == 0)
    out[0] = (r[0] + r[1] + r[2] + r[3]) * (1.0f / (float)N);
}

extern "C" void kernel_launch(void* const* d_in, const int* in_sizes, int n_in,
                              void* d_out, int out_size, void* d_ws, size_t ws_size,
                              hipStream_t stream)
{
  const float* inputs = (const float*)d_in[0];
  const float* noise  = (const float*)d_in[1];

  char* ws = (char*)d_ws;
  __hip_bfloat16* aB = (__hip_bfloat16*)ws;                       // 16 MB
  __hip_bfloat16* bB = aB + (size_t)N * D;                        // 16 MB
  float* S    = (float*)(bB + (size_t)N * D);                     // 32 KB
  float* diag = S + N;                                            // 32 KB

  UCR_prep<<<N, 256, 0, stream>>>(inputs, noise, aB, bB, diag, S);
  UCR_gemm<<<(N / 256) * (N / 256), 512, 0, stream>>>(aB, bB, S);
  UCR_loss<<<1, 256, 0, stream>>>(S, diag, (float*)d_out);
}

// Round 7
// 246.707 us; speedup vs baseline: 1.2587x; 1.2587x over previous
//
#include <hip/hip_runtime.h>
#include <hip/hip_bf16.h>

#define N 8192
#define D 1024
#define BM 128
#define BN 256
#define BK 32
#define NKT (D / BK)   // 32

static constexpr float TEMP = 0.1f;
static constexpr float KEEP = 0.9f;
static constexpr float EPSN = 1e-8f;

typedef __attribute__((ext_vector_type(8))) short bf16x8;
typedef __attribute__((ext_vector_type(4))) float f32x4;

__device__ __forceinline__ void gload_lds16(const void* gsrc, void* ldst) {
  __builtin_amdgcn_global_load_lds(
      (const __attribute__((address_space(1))) void*)gsrc,
      (__attribute__((address_space(3))) void*)ldst, 16, 0, 0);
}

// ---------------- Kernel A: norms + diag + bf16 convert (scales folded) ----
struct bf4pack { __hip_bfloat16 v[4]; };

__global__ __launch_bounds__(256) void UCR_prep(
    const float* __restrict__ inputs, const float* __restrict__ noise,
    __hip_bfloat16* __restrict__ aB, __hip_bfloat16* __restrict__ bB,
    float* __restrict__ diag, float* __restrict__ S, float* __restrict__ out)
{
  const int row = blockIdx.x;
  const int t = threadIdx.x;
  const float4 x = ((const float4*)(inputs + (size_t)row * D))[t];
  const float4 u = ((const float4*)(noise  + (size_t)row * D))[t];
  const float inv_keep = 1.0f / KEEP;
  float4 e;
  e.x = (u.x < KEEP) ? x.x * inv_keep : 0.0f;
  e.y = (u.y < KEEP) ? x.y * inv_keep : 0.0f;
  e.z = (u.z < KEEP) ? x.z * inv_keep : 0.0f;
  e.w = (u.w < KEEP) ? x.w * inv_keep : 0.0f;

  float sx  = x.x*x.x + x.y*x.y + x.z*x.z + x.w*x.w;
  float se  = e.x*e.x + e.y*e.y + e.z*e.z + e.w*e.w;
  float sxe = x.x*e.x + x.y*e.y + x.z*e.z + x.w*e.w;

  #pragma unroll
  for (int off = 1; off < 64; off <<= 1) {
    sx  += __shfl_xor(sx, off);
    se  += __shfl_xor(se, off);
    sxe += __shfl_xor(sxe, off);
  }
  __shared__ float red[3][4];
  const int wid = t >> 6, lane = t & 63;
  if (lane == 0) { red[0][wid] = sx; red[1][wid] = se; red[2][wid] = sxe; }
  __syncthreads();
  sx  = red[0][0] + red[0][1] + red[0][2] + red[0][3];
  se  = red[1][0] + red[1][1] + red[1][2] + red[1][3];
  sxe = red[2][0] + red[2][1] + red[2][2] + red[2][3];

  const float na = fmaxf(sqrtf(sx), EPSN);
  const float nb = fmaxf(sqrtf(se), EPSN);
  const float sa = 1.0f / (na * TEMP);
  const float sb = 1.0f / nb;
  if (t == 0) {
    diag[row] = sxe / (na * nb * TEMP);
    S[row] = 0.0f;
    if (row == 0) out[0] = 0.0f;
  }

  bf4pack pa, pb;
  pa.v[0] = __float2bfloat16(x.x * sa); pa.v[1] = __float2bfloat16(x.y * sa);
  pa.v[2] = __float2bfloat16(x.z * sa); pa.v[3] = __float2bfloat16(x.w * sa);
  pb.v[0] = __float2bfloat16(e.x * sb); pb.v[1] = __float2bfloat16(e.y * sb);
  pb.v[2] = __float2bfloat16(e.z * sb); pb.v[3] = __float2bfloat16(e.w * sb);
  ((bf4pack*)(aB + (size_t)row * D))[t] = pa;
  ((bf4pack*)(bB + (size_t)row * D))[t] = pb;
}

// ---------------- Kernel B: 128x256 tile, BK=32, 3-slot ring, 2 blocks/CU --
// 4 waves (wave-tile 128x64), 72 KB LDS -> TWO blocks co-resident per CU ->
// two independent barrier domains; block B's read/stage phases overlap block
// A's MFMA phases (m114: MFMA and LDS pipes co-schedule across waves).
// Slot = 24 KB (A[128][32] + B[256][32]). Stage kt+2 at top of kt; vmcnt(6)
// at bottom retires kt+1's 6 loads (issued 2 iterations earlier). One
// barrier per kt. No asm around ds_reads (compiler schedules; m141 lesson).
// Swizzle (64 B rows): byte ^= ((byte>>7)&3)<<4 both-sides involution:
// linear gload_lds dest + inverse-swizzled global src + swizzled ds_read
// (round-3-measured: 0 bank conflicts with this exact pattern at BK=32).
__global__ __launch_bounds__(256, 2) void UCR_gemm(
    const __hip_bfloat16* __restrict__ Aw, const __hip_bfloat16* __restrict__ Bw,
    float* __restrict__ S)
{
  __shared__ char lds[73728];

  const int t = threadIdx.x;            // 0..255
  const int lane = t & 63;
  const int wid = t >> 6;               // 0..3 = col quarter (64 cols each)

  // L2 window mapping: XCD (bid&7) owns tm-slab [xcd*8, xcd*8+8) (A-slab
  // 2 MB, L2-resident); within the slab tm cycles fast, tn slow (8
  // consecutive blocks per XCD share one 512 KB B-tile). 2048 blocks.
  const int bid = blockIdx.x;
  const int u = bid >> 3;
  const int tm = (bid & 7) * 8 + (u & 7);   // 0..63
  const int tn = u >> 3;                    // 0..31

  const char* Ag = (const char*)(Aw + (size_t)tm * BM * D);
  const char* Bg = (const char*)(Bw + (size_t)tn * BN * D);

  // staging: linear LDS dest x -> inverse-swizzled global source (rule 21)
  const char* aS[2]; const char* bS[4]; unsigned xA[2], xB[4];
  #pragma unroll
  for (int j = 0; j < 2; ++j) {
    const unsigned x = (unsigned)t * 16u + (unsigned)j * 4096u;
    const unsigned lin = x ^ (((x >> 7) & 3u) << 4);
    aS[j] = Ag + (size_t)(lin >> 6) * 2048 + (lin & 63u);
    xA[j] = x;
  }
  #pragma unroll
  for (int j = 0; j < 4; ++j) {
    const unsigned x = (unsigned)t * 16u + (unsigned)j * 4096u;
    const unsigned lin = x ^ (((x >> 7) & 3u) << 4);
    bS[j] = Bg + (size_t)(lin >> 6) * 2048 + (lin & 63u);
    xB[j] = x;
  }

#define STAGE(kt, L) do {                                   \
    gload_lds16(aS[0] + (kt) * 64, (L) + xA[0]);            \
    gload_lds16(aS[1] + (kt) * 64, (L) + xA[1]);            \
    gload_lds16(bS[0] + (kt) * 64, (L) + 8192 + xB[0]);     \
    gload_lds16(bS[1] + (kt) * 64, (L) + 8192 + xB[1]);     \
    gload_lds16(bS[2] + (kt) * 64, (L) + 8192 + xB[2]);     \
    gload_lds16(bS[3] + (kt) * 64, (L) + 8192 + xB[3]);     \
  } while (0)

  // fragment read addressing; swizzle key for row r is (r>>1)&3 = (ln>>1)&3
  const int ln = lane & 15;
  const int cq = lane >> 4;
  const int colk = (cq * 16) ^ (((ln >> 1) & 3) << 4);
  const int aoff = ln * 64 + colk;                          // + m*1024
  const int boff = 8192 + wid * 4096 + ln * 64 + colk;      // + n*1024

  f32x4 acc[8][4] = {};

  char* L0 = lds;
  char* L1 = lds + 24576;
  char* L2 = lds + 49152;

  // prologue: tiles 0,1 staged; wait tile 0 landed
  STAGE(0, L0); STAGE(1, L1);
  asm volatile("s_waitcnt vmcnt(6)" ::: "memory");
  __builtin_amdgcn_s_barrier();

  for (int kt = 0; kt < NKT - 2; ++kt) {
    STAGE(kt + 2, L2);
    bf16x8 aF[8], bF[4];
    #pragma unroll
    for (int m = 0; m < 8; ++m)
      aF[m] = *(const bf16x8*)(L0 + m * 1024 + aoff);
    #pragma unroll
    for (int n = 0; n < 4; ++n)
      bF[n] = *(const bf16x8*)(L0 + n * 1024 + boff);
    __builtin_amdgcn_s_setprio(1);
    #pragma unroll
    for (int m = 0; m < 8; ++m)
      #pragma unroll
      for (int n = 0; n < 4; ++n)
        acc[m][n] = __builtin_amdgcn_mfma_f32_16x16x32_bf16(
            aF[m], bF[n], acc[m][n], 0, 0, 0);
    __builtin_amdgcn_s_setprio(0);
    asm volatile("s_waitcnt vmcnt(6)" ::: "memory");  // kt+1's loads landed
    __builtin_amdgcn_s_barrier();
    char* tmp = L0; L0 = L1; L1 = L2; L2 = tmp;
  }
  // kt = NKT-2: no stage; drain so tile NKT-1 is resident
  {
    bf16x8 aF[8], bF[4];
    #pragma unroll
    for (int m = 0; m < 8; ++m)
      aF[m] = *(const bf16x8*)(L0 + m * 1024 + aoff);
    #pragma unroll
    for (int n = 0; n < 4; ++n)
      bF[n] = *(const bf16x8*)(L0 + n * 1024 + boff);
    __builtin_amdgcn_s_setprio(1);
    #pragma unroll
    for (int m = 0; m < 8; ++m)
      #pragma unroll
      for (int n = 0; n < 4; ++n)
        acc[m][n] = __builtin_amdgcn_mfma_f32_16x16x32_bf16(
            aF[m], bF[n], acc[m][n], 0, 0, 0);
    __builtin_amdgcn_s_setprio(0);
    asm volatile("s_waitcnt vmcnt(0)" ::: "memory");
    __builtin_amdgcn_s_barrier();
    char* tmp = L0; L0 = L1; L1 = L2; L2 = tmp;
  }
  // kt = NKT-1: final tile, no stage/wait
  {
    bf16x8 aF[8], bF[4];
    #pragma unroll
    for (int m = 0; m < 8; ++m)
      aF[m] = *(const bf16x8*)(L0 + m * 1024 + aoff);
    #pragma unroll
    for (int n = 0; n < 4; ++n)
      bF[n] = *(const bf16x8*)(L0 + n * 1024 + boff);
    #pragma unroll
    for (int m = 0; m < 8; ++m)
      #pragma unroll
      for (int n = 0; n < 4; ++n)
        acc[m][n] = __builtin_amdgcn_mfma_f32_16x16x32_bf16(
            aF[m], bF[n], acc[m][n], 0, 0, 0);
  }
#undef STAGE

  // epilogue: C/D frag layout col=lane&15, row=(lane>>4)*4+i (m89-verified)
  const int g = lane >> 4;
  const int c = lane & 15;
  const int rowbase = tm * BM;
  #pragma unroll
  for (int m = 0; m < 8; ++m) {
    #pragma unroll
    for (int i = 0; i < 4; ++i) {
      float s = 0.0f;
      #pragma unroll
      for (int n = 0; n < 4; ++n) s += __expf(acc[m][n][i]);
      #pragma unroll
      for (int off = 1; off < 16; off <<= 1) s += __shfl_xor(s, off);
      if (c == 0) atomicAdd(&S[rowbase + m * 16 + g * 4 + i], s);
    }
  }
}

// ---------------- Kernel C: loss = mean(log(S) - diag), parallel -----------
__global__ __launch_bounds__(256) void UCR_loss(
    const float* __restrict__ S, const float* __restrict__ diag,
    float* __restrict__ out)
{
  const int i = blockIdx.x * 256 + threadIdx.x;
  float acc = logf(S[i]) - diag[i];
  #pragma unroll
  for (int off = 1; off < 64; off <<= 1) acc += __shfl_xor(acc, off);
  __shared__ float r[4];
  if ((threadIdx.x & 63) == 0) r[threadIdx.x >> 6] = acc;
  __syncthreads();
  if (threadIdx.x == 0)
    atomicAdd(out, (r[0] + r[1] + r[2] + r[3]) * (1.0f / (float)N));
}

extern "C" void kernel_launch(void* const* d_in, const int* in_sizes, int n_in,
                              void* d_out, int out_size, void* d_ws, size_t ws_size,
                              hipStream_t stream)
{
  const float* inputs = (const float*)d_in[0];
  const float* noise  = (const float*)d_in[1];

  char* ws = (char*)d_ws;
  __hip_bfloat16* aB = (__hip_bfloat16*)ws;                       // 16 MB
  __hip_bfloat16* bB = aB + (size_t)N * D;                        // 16 MB
  float* S    = (float*)(bB + (size_t)N * D);                     // 32 KB
  float* diag = S + N;                                            // 32 KB

  UCR_prep<<<N, 256, 0, stream>>>(inputs, noise, aB, bB, diag, S, (float*)d_out);
  UCR_gemm<<<(N / BM) * (N / BN), 256, 0, stream>>>(aB, bB, S);
  UCR_loss<<<N / 256, 256, 0, stream>>>(S, diag, (float*)d_out);
}

// Round 8
// 244.115 us; speedup vs baseline: 1.2720x; 1.0106x over previous
//
#include <hip/hip_runtime.h>
#include <hip/hip_bf16.h>

#define N 8192
#define D 1024
#define BM 128
#define BN 256
#define BK 64            // 64 fp8 elements = 64 B rows
#define NKT (D / BK)     // 16

static constexpr float TEMP = 0.1f;
static constexpr float KEEP = 0.9f;
static constexpr float EPSN = 1e-8f;
static constexpr float INVS = 1.0f / 1024.0f;   // undo a*16, b*64 scaling

typedef __attribute__((ext_vector_type(4))) float f32x4;

__device__ __forceinline__ void gload_lds16(const void* gsrc, void* ldst) {
  __builtin_amdgcn_global_load_lds(
      (const __attribute__((address_space(1))) void*)gsrc,
      (__attribute__((address_space(3))) void*)ldst, 16, 0, 0);
}

// ---------------- Kernel A: norms + diag + fp8 e4m3 convert (scales folded)
// a8[n][d] = fp8( inputs[n][d] * 16/(na*TEMP) )   (sigma ~5, well in e4m3)
// b8[n][d] = fp8( enhanced[n][d] * 64/nb )        (sigma ~2)
// diag[n]  = exact fp32 logit_nn (used for lse diagonal substitution AND loss)
__global__ __launch_bounds__(256) void UCR_prep(
    const float* __restrict__ inputs, const float* __restrict__ noise,
    unsigned char* __restrict__ a8, unsigned char* __restrict__ b8,
    float* __restrict__ diag, float* __restrict__ S, float* __restrict__ out)
{
  const int row = blockIdx.x;
  const int t = threadIdx.x;
  const float4 x = ((const float4*)(inputs + (size_t)row * D))[t];
  const float4 u = ((const float4*)(noise  + (size_t)row * D))[t];
  const float inv_keep = 1.0f / KEEP;
  float4 e;
  e.x = (u.x < KEEP) ? x.x * inv_keep : 0.0f;
  e.y = (u.y < KEEP) ? x.y * inv_keep : 0.0f;
  e.z = (u.z < KEEP) ? x.z * inv_keep : 0.0f;
  e.w = (u.w < KEEP) ? x.w * inv_keep : 0.0f;

  float sx  = x.x*x.x + x.y*x.y + x.z*x.z + x.w*x.w;
  float se  = e.x*e.x + e.y*e.y + e.z*e.z + e.w*e.w;
  float sxe = x.x*e.x + x.y*e.y + x.z*e.z + x.w*e.w;

  #pragma unroll
  for (int off = 1; off < 64; off <<= 1) {
    sx  += __shfl_xor(sx, off);
    se  += __shfl_xor(se, off);
    sxe += __shfl_xor(sxe, off);
  }
  __shared__ float red[3][4];
  const int wid = t >> 6, lane = t & 63;
  if (lane == 0) { red[0][wid] = sx; red[1][wid] = se; red[2][wid] = sxe; }
  __syncthreads();
  sx  = red[0][0] + red[0][1] + red[0][2] + red[0][3];
  se  = red[1][0] + red[1][1] + red[1][2] + red[1][3];
  sxe = red[2][0] + red[2][1] + red[2][2] + red[2][3];

  const float na = fmaxf(sqrtf(sx), EPSN);
  const float nb = fmaxf(sqrtf(se), EPSN);
  const float sa = 16.0f / (na * TEMP);
  const float sb = 64.0f / nb;
  if (t == 0) {
    diag[row] = sxe / (na * nb * TEMP);
    S[row] = 0.0f;
    if (row == 0) out[0] = 0.0f;
  }

  int pa = __builtin_amdgcn_cvt_pk_fp8_f32(x.x * sa, x.y * sa, 0, false);
  pa     = __builtin_amdgcn_cvt_pk_fp8_f32(x.z * sa, x.w * sa, pa, true);
  int pb = __builtin_amdgcn_cvt_pk_fp8_f32(e.x * sb, e.y * sb, 0, false);
  pb     = __builtin_amdgcn_cvt_pk_fp8_f32(e.z * sb, e.w * sb, pb, true);
  ((int*)(a8 + (size_t)row * D))[t] = pa;
  ((int*)(b8 + (size_t)row * D))[t] = pb;
}

// ---------------- Kernel B: fp8 GEMM 128x256, BK=64, 3-slot ring, 2 blk/CU -
// Same schedule as round 7 (proven: 2 barrier domains anti-phase). fp8 halves
// LDS bytes/FLOP: slot = A[128][64B] + B[256][64B] = 24 KB; frag = ds_read_b64.
// Swizzle (64 B rows, 16-B granular so gload stays contiguous):
//   swz(x) = x ^ (((x>>7)&3)<<4)  involution; b64 reads distribute 4 lanes
//   per bank-pair = exact 512B/128B floor -> 0 extra conflicts.
// Diagonal blocks (tn == tm>>1) substitute exact fp32 diag before exp.
__global__ __launch_bounds__(256, 2) void UCR_gemm(
    const unsigned char* __restrict__ Aw, const unsigned char* __restrict__ Bw,
    const float* __restrict__ diag, float* __restrict__ S)
{
  __shared__ char lds[73728];

  const int t = threadIdx.x;            // 0..255
  const int lane = t & 63;
  const int wid = t >> 6;               // 0..3 = col quarter (64 cols each)

  // L2 window mapping (round-7-verified: FETCH 270->96 MB): XCD (bid&7) owns
  // tm-slab; tm fast, tn slow. 2048 blocks.
  const int bid = blockIdx.x;
  const int u = bid >> 3;
  const int tm = (bid & 7) * 8 + (u & 7);   // 0..63
  const int tn = u >> 3;                    // 0..31

  const char* Ag = (const char*)(Aw + (size_t)tm * BM * D);
  const char* Bg = (const char*)(Bw + (size_t)tn * BN * D);

  // staging: linear LDS dest x -> inverse-swizzled global source (rule 21)
  const char* aS[2]; const char* bS[4]; unsigned xA[2], xB[4];
  #pragma unroll
  for (int j = 0; j < 2; ++j) {
    const unsigned x = (unsigned)t * 16u + (unsigned)j * 4096u;
    const unsigned lin = x ^ (((x >> 7) & 3u) << 4);
    aS[j] = Ag + (size_t)(lin >> 6) * D + (lin & 63u);
    xA[j] = x;
  }
  #pragma unroll
  for (int j = 0; j < 4; ++j) {
    const unsigned x = (unsigned)t * 16u + (unsigned)j * 4096u;
    const unsigned lin = x ^ (((x >> 7) & 3u) << 4);
    bS[j] = Bg + (size_t)(lin >> 6) * D + (lin & 63u);
    xB[j] = x;
  }

#define STAGE(kt, L) do {                                   \
    gload_lds16(aS[0] + (kt) * 64, (L) + xA[0]);            \
    gload_lds16(aS[1] + (kt) * 64, (L) + xA[1]);            \
    gload_lds16(bS[0] + (kt) * 64, (L) + 8192 + xB[0]);     \
    gload_lds16(bS[1] + (kt) * 64, (L) + 8192 + xB[1]);     \
    gload_lds16(bS[2] + (kt) * 64, (L) + 8192 + xB[2]);     \
    gload_lds16(bS[3] + (kt) * 64, (L) + 8192 + xB[3]);     \
  } while (0)

  // fragment read addressing: lane (ln,cq) reads row ln(+16m), K-bytes
  // [ks*32 + cq*8, +8). swizzle key = ((row>>1)&3)<<4, row-invariant per
  // frag step (16-row stride). off_k1 = off_k0 ^ 32 (bit5 untouched by key).
  const int ln = lane & 15;
  const int cq = lane >> 4;
  const int offk0 = (cq * 8) ^ (((ln >> 1) & 3) << 4);
  const int aoff = ln * 64 + offk0;                       // + m*1024 (+32 ks)
  const int boff = 8192 + wid * 4096 + ln * 64 + offk0;   // + n*1024 (+32 ks)

  f32x4 acc[8][4] = {};

  char* L0 = lds;
  char* L1 = lds + 24576;
  char* L2 = lds + 49152;

  // prologue: tiles 0,1 staged; wait tile 0 landed
  STAGE(0, L0); STAGE(1, L1);
  asm volatile("s_waitcnt vmcnt(6)" ::: "memory");
  __builtin_amdgcn_s_barrier();

  for (int kt = 0; kt < NKT - 2; ++kt) {
    STAGE(kt + 2, L2);
    long aF[8][2], bF[4][2];
    #pragma unroll
    for (int m = 0; m < 8; ++m) {
      aF[m][0] = *(const long*)(L0 + m * 1024 + aoff);
      aF[m][1] = *(const long*)(L0 + m * 1024 + (aoff ^ 32));
    }
    #pragma unroll
    for (int n = 0; n < 4; ++n) {
      bF[n][0] = *(const long*)(L0 + n * 1024 + boff);
      bF[n][1] = *(const long*)(L0 + n * 1024 + (boff ^ 32));
    }
    __builtin_amdgcn_s_setprio(1);
    #pragma unroll
    for (int ks = 0; ks < 2; ++ks)
      #pragma unroll
      for (int m = 0; m < 8; ++m)
        #pragma unroll
        for (int n = 0; n < 4; ++n)
          acc[m][n] = __builtin_amdgcn_mfma_f32_16x16x32_fp8_fp8(
              aF[m][ks], bF[n][ks], acc[m][n], 0, 0, 0);
    __builtin_amdgcn_s_setprio(0);
    asm volatile("s_waitcnt vmcnt(6)" ::: "memory");  // kt+1's loads landed
    __builtin_amdgcn_s_barrier();
    char* tmp = L0; L0 = L1; L1 = L2; L2 = tmp;
  }
  // kt = NKT-2: no stage; drain so tile NKT-1 is resident
  {
    long aF[8][2], bF[4][2];
    #pragma unroll
    for (int m = 0; m < 8; ++m) {
      aF[m][0] = *(const long*)(L0 + m * 1024 + aoff);
      aF[m][1] = *(const long*)(L0 + m * 1024 + (aoff ^ 32));
    }
    #pragma unroll
    for (int n = 0; n < 4; ++n) {
      bF[n][0] = *(const long*)(L0 + n * 1024 + boff);
      bF[n][1] = *(const long*)(L0 + n * 1024 + (boff ^ 32));
    }
    __builtin_amdgcn_s_setprio(1);
    #pragma unroll
    for (int ks = 0; ks < 2; ++ks)
      #pragma unroll
      for (int m = 0; m < 8; ++m)
        #pragma unroll
        for (int n = 0; n < 4; ++n)
          acc[m][n] = __builtin_amdgcn_mfma_f32_16x16x32_fp8_fp8(
              aF[m][ks], bF[n][ks], acc[m][n], 0, 0, 0);
    __builtin_amdgcn_s_setprio(0);
    asm volatile("s_waitcnt vmcnt(0)" ::: "memory");
    __builtin_amdgcn_s_barrier();
    char* tmp = L0; L0 = L1; L1 = L2; L2 = tmp;
  }
  // kt = NKT-1: final tile, no stage/wait
  {
    long aF[8][2], bF[4][2];
    #pragma unroll
    for (int m = 0; m < 8; ++m) {
      aF[m][0] = *(const long*)(L0 + m * 1024 + aoff);
      aF[m][1] = *(const long*)(L0 + m * 1024 + (aoff ^ 32));
    }
    #pragma unroll
    for (int n = 0; n < 4; ++n) {
      bF[n][0] = *(const long*)(L0 + n * 1024 + boff);
      bF[n][1] = *(const long*)(L0 + n * 1024 + (boff ^ 32));
    }
    #pragma unroll
    for (int ks = 0; ks < 2; ++ks)
      #pragma unroll
      for (int m = 0; m < 8; ++m)
        #pragma unroll
        for (int n = 0; n < 4; ++n)
          acc[m][n] = __builtin_amdgcn_mfma_f32_16x16x32_fp8_fp8(
              aF[m][ks], bF[n][ks], acc[m][n], 0, 0, 0);
  }
#undef STAGE

  // epilogue: C/D frag layout col=lane&15, row=(lane>>4)*4+i (dtype-indep).
  // Diagonal tiles substitute exact fp32 diag logit before exp.
  const int g = lane >> 4;
  const int cc = lane & 15;
  const int rowbase = tm * BM;
  const int colb = tn * BN + wid * 64;
  const bool hasdiag = (tn == (tm >> 1));
  #pragma unroll
  for (int m = 0; m < 8; ++m) {
    #pragma unroll
    for (int i = 0; i < 4; ++i) {
      const int row = rowbase + m * 16 + g * 4 + i;
      const float dv = hasdiag ? diag[row] : 0.0f;
      float s = 0.0f;
      #pragma unroll
      for (int n = 0; n < 4; ++n) {
        float v = acc[m][n][i] * INVS;
        if (hasdiag && (colb + n * 16 + cc) == row) v = dv;
        s += __expf(v);
      }
      #pragma unroll
      for (int off = 1; off < 16; off <<= 1) s += __shfl_xor(s, off);
      if (cc == 0) atomicAdd(&S[row], s);
    }
  }
}

// ---------------- Kernel C: loss = mean(log(S) - diag), parallel -----------
__global__ __launch_bounds__(256) void UCR_loss(
    const float* __restrict__ S, const float* __restrict__ diag,
    float* __restrict__ out)
{
  const int i = blockIdx.x * 256 + threadIdx.x;
  float acc = logf(S[i]) - diag[i];
  #pragma unroll
  for (int off = 1; off < 64; off <<= 1) acc += __shfl_xor(acc, off);
  __shared__ float r[4];
  if ((threadIdx.x & 63) == 0) r[threadIdx.x >> 6] = acc;
  __syncthreads();
  if (threadIdx.x == 0)
    atomicAdd(out, (r[0] + r[1] + r[2] + r[3]) * (1.0f / (float)N));
}

extern "C" void kernel_launch(void* const* d_in, const int* in_sizes, int n_in,
                              void* d_out, int out_size, void* d_ws, size_t ws_size,
                              hipStream_t stream)
{
  const float* inputs = (const float*)d_in[0];
  const float* noise  = (const float*)d_in[1];

  char* ws = (char*)d_ws;
  unsigned char* a8 = (unsigned char*)ws;                         // 8 MB
  unsigned char* b8 = a8 + (size_t)N * D;                         // 8 MB
  float* S    = (float*)(b8 + (size_t)N * D);                     // 32 KB
  float* diag = S + N;                                            // 32 KB

  UCR_prep<<<N, 256, 0, stream>>>(inputs, noise, a8, b8, diag, S, (float*)d_out);
  UCR_gemm<<<(N / BM) * (N / BN), 256, 0, stream>>>(a8, b8, diag, S);
  UCR_loss<<<N / 256, 256, 0, stream>>>(S, diag, (float*)d_out);
}